// Round 1
// baseline (655.074 us; speedup 1.0000x reference)
//
#include <hip/hip_runtime.h>
#include <math.h>

#define NN 50000
#define NE 600000
#define DIM 128
#define LAYERS 3
#define BN_EPS 1e-5f

// ---------------------------------------------------------------- init ----
__global__ void k_init(int* __restrict__ deg, float* __restrict__ bnstats) {
    int i = blockIdx.x * 256 + threadIdx.x;
    if (i < NN) deg[i] = 0;
    if (i < LAYERS * 2 * DIM) bnstats[i] = 0.0f;
}

// ----------------------------------------------------------- histogram ----
__global__ void k_hist(const int* __restrict__ dst, int* __restrict__ deg) {
    int e = blockIdx.x * 256 + threadIdx.x;
    if (e < NE) atomicAdd(&deg[dst[e]], 1);
}

// ------------------------------------------- exclusive scan (1 block) ----
__global__ void k_scan(const int* __restrict__ deg, int* __restrict__ off) {
    __shared__ int buf[1024];
    __shared__ int carry_s;
    const int t = threadIdx.x;
    if (t == 0) { carry_s = 0; off[0] = 0; }
    __syncthreads();
    for (int base = 0; base < NN; base += 1024) {
        int v = (base + t < NN) ? deg[base + t] : 0;
        buf[t] = v;
        __syncthreads();
        for (int s = 1; s < 1024; s <<= 1) {
            int add = (t >= s) ? buf[t - s] : 0;
            __syncthreads();
            buf[t] += add;
            __syncthreads();
        }
        if (base + t < NN) off[base + t + 1] = carry_s + buf[t];
        __syncthreads();
        if (t == 0) carry_s += buf[1023];
        __syncthreads();
    }
}

// ------------------------------------------------------- cursor = off ----
__global__ void k_copy(const int* __restrict__ off, int* __restrict__ cur) {
    int i = blockIdx.x * 256 + threadIdx.x;
    if (i < NN) cur[i] = off[i];
}

// ------------------------------------------------------------ csr fill ----
__global__ void k_fill(const int* __restrict__ src, const int* __restrict__ dst,
                       int* __restrict__ cur, int* __restrict__ csr) {
    int e = blockIdx.x * 256 + threadIdx.x;
    if (e < NE) {
        int p = atomicAdd(&cur[dst[e]], 1);
        csr[p] = src[e];
    }
}

// --------------------------------------- aggregate: z = h + sum_in h ----
// one wave per node; lane holds 2 features (float2) -> 512B coalesced rows
__global__ __launch_bounds__(256) void k_agg(const float* __restrict__ h,
                                             const int* __restrict__ off,
                                             const int* __restrict__ csr,
                                             float* __restrict__ z) {
    int wid  = (blockIdx.x * 256 + threadIdx.x) >> 6;
    int lane = threadIdx.x & 63;
    if (wid >= NN) return;
    const int start = off[wid], end = off[wid + 1];
    float2 acc = *(const float2*)&h[(size_t)wid * DIM + lane * 2];
    int i = start;
    for (; i + 1 < end; i += 2) {           // unroll-2: two loads in flight
        int s0 = csr[i], s1 = csr[i + 1];
        float2 v0 = *(const float2*)&h[(size_t)s0 * DIM + lane * 2];
        float2 v1 = *(const float2*)&h[(size_t)s1 * DIM + lane * 2];
        acc.x += v0.x + v1.x;
        acc.y += v0.y + v1.y;
    }
    if (i < end) {
        int s0 = csr[i];
        float2 v0 = *(const float2*)&h[(size_t)s0 * DIM + lane * 2];
        acc.x += v0.x;
        acc.y += v0.y;
    }
    *(float2*)&z[(size_t)wid * DIM + lane * 2] = acc;
}

// -------------------------------- fused MLP: relu(zW1+b1)W2+b2, stats ----
// 32-row tile; z updated in place (pre-BN); per-block BN partials -> atomics
#define TM 32
__global__ __launch_bounds__(256, 2) void k_mlp(float* __restrict__ z,
                                                const float* __restrict__ W1,
                                                const float* __restrict__ b1,
                                                const float* __restrict__ W2,
                                                const float* __restrict__ b2,
                                                float* __restrict__ bnsum,
                                                float* __restrict__ bnsq) {
    __shared__ float zt[TM][DIM];   // 16 KB  (A tile, then y1 tile, then stats scratch)
    __shared__ float w[DIM][DIM];   // 64 KB  (W1, then W2)
    const int t = threadIdx.x;
    const int c = t & 31;           // cols 4c..4c+3
    const int r = t >> 5;           // rows 4r..4r+3
    const int row0 = blockIdx.x * TM;

    // ---- load z tile (guarded) + W1 ----
    #pragma unroll
    for (int i = 0; i < 4; ++i) {
        int f4 = t + i * 256;
        int rr = f4 >> 5, c4 = f4 & 31;
        int g  = row0 + rr;
        float4 v = make_float4(0.f, 0.f, 0.f, 0.f);
        if (g < NN) v = *(const float4*)&z[(size_t)g * DIM + c4 * 4];
        *(float4*)&zt[rr][c4 * 4] = v;
    }
    #pragma unroll
    for (int i = 0; i < 16; ++i) {
        int f4 = t + i * 256;
        int k = f4 >> 5, j4 = f4 & 31;
        *(float4*)&w[k][j4 * 4] = *(const float4*)&W1[k * DIM + j4 * 4];
    }
    __syncthreads();

    // ---- GEMM1 ----
    float acc[4][4];
    #pragma unroll
    for (int i = 0; i < 4; ++i)
        #pragma unroll
        for (int j = 0; j < 4; ++j) acc[i][j] = 0.0f;

    for (int k = 0; k < DIM; k += 4) {
        float4 a4[4];
        #pragma unroll
        for (int i = 0; i < 4; ++i) a4[i] = *(const float4*)&zt[r * 4 + i][k];
        #pragma unroll
        for (int kk = 0; kk < 4; ++kk) {
            const float4 b = *(const float4*)&w[k + kk][c * 4];
            #pragma unroll
            for (int i = 0; i < 4; ++i) {
                const float a = (&a4[i].x)[kk];
                acc[i][0] = fmaf(a, b.x, acc[i][0]);
                acc[i][1] = fmaf(a, b.y, acc[i][1]);
                acc[i][2] = fmaf(a, b.z, acc[i][2]);
                acc[i][3] = fmaf(a, b.w, acc[i][3]);
            }
        }
    }
    __syncthreads();   // everyone done reading zt & w

    // ---- bias1 + relu -> y1 into zt; reload w with W2 ----
    const float4 bias1 = *(const float4*)&b1[c * 4];
    #pragma unroll
    for (int i = 0; i < 4; ++i) {
        float4 y;
        y.x = fmaxf(acc[i][0] + bias1.x, 0.f);
        y.y = fmaxf(acc[i][1] + bias1.y, 0.f);
        y.z = fmaxf(acc[i][2] + bias1.z, 0.f);
        y.w = fmaxf(acc[i][3] + bias1.w, 0.f);
        *(float4*)&zt[r * 4 + i][c * 4] = y;
    }
    #pragma unroll
    for (int i = 0; i < 16; ++i) {
        int f4 = t + i * 256;
        int k = f4 >> 5, j4 = f4 & 31;
        *(float4*)&w[k][j4 * 4] = *(const float4*)&W2[k * DIM + j4 * 4];
    }
    __syncthreads();

    // ---- GEMM2 ----
    #pragma unroll
    for (int i = 0; i < 4; ++i)
        #pragma unroll
        for (int j = 0; j < 4; ++j) acc[i][j] = 0.0f;

    for (int k = 0; k < DIM; k += 4) {
        float4 a4[4];
        #pragma unroll
        for (int i = 0; i < 4; ++i) a4[i] = *(const float4*)&zt[r * 4 + i][k];
        #pragma unroll
        for (int kk = 0; kk < 4; ++kk) {
            const float4 b = *(const float4*)&w[k + kk][c * 4];
            #pragma unroll
            for (int i = 0; i < 4; ++i) {
                const float a = (&a4[i].x)[kk];
                acc[i][0] = fmaf(a, b.x, acc[i][0]);
                acc[i][1] = fmaf(a, b.y, acc[i][1]);
                acc[i][2] = fmaf(a, b.z, acc[i][2]);
                acc[i][3] = fmaf(a, b.w, acc[i][3]);
            }
        }
    }
    __syncthreads();   // before reusing zt as stats scratch

    // ---- bias2, write z (pre-BN) back, per-thread stats ----
    const float4 bias2 = *(const float4*)&b2[c * 4];
    float s[4] = {0.f, 0.f, 0.f, 0.f};
    float q[4] = {0.f, 0.f, 0.f, 0.f};
    #pragma unroll
    for (int i = 0; i < 4; ++i) {
        int g = row0 + r * 4 + i;
        float4 zv;
        zv.x = acc[i][0] + bias2.x;
        zv.y = acc[i][1] + bias2.y;
        zv.z = acc[i][2] + bias2.z;
        zv.w = acc[i][3] + bias2.w;
        if (g < NN) {
            *(float4*)&z[(size_t)g * DIM + c * 4] = zv;
            s[0] += zv.x; s[1] += zv.y; s[2] += zv.z; s[3] += zv.w;
            q[0] += zv.x * zv.x; q[1] += zv.y * zv.y;
            q[2] += zv.z * zv.z; q[3] += zv.w * zv.w;
        }
    }
    // block reduce over the 8 row-groups via LDS, then one atomic per col
    float* scratch = &zt[0][0];     // 4096 floats: [0:1024)=sum, [1024:2048)=sq
    #pragma unroll
    for (int j = 0; j < 4; ++j) {
        scratch[r * DIM + c * 4 + j]        = s[j];
        scratch[1024 + r * DIM + c * 4 + j] = q[j];
    }
    __syncthreads();
    if (t < DIM) {
        float ss = 0.f, qq = 0.f;
        #pragma unroll
        for (int rr = 0; rr < 8; ++rr) {
            ss += scratch[rr * DIM + t];
            qq += scratch[1024 + rr * DIM + t];
        }
        atomicAdd(&bnsum[t], ss);
        atomicAdd(&bnsq[t], qq);
    }
}

// ------------------------------- BN finalize + normalize + relu -> h ----
__global__ __launch_bounds__(256) void k_norm(const float* __restrict__ z,
                                              const float* __restrict__ bnsum,
                                              const float* __restrict__ bnsq,
                                              const float* __restrict__ gamma,
                                              const float* __restrict__ beta,
                                              float* __restrict__ h) {
    int f4 = blockIdx.x * 256 + threadIdx.x;          // over N*DIM/4 float4
    if (f4 >= NN * DIM / 4) return;
    int c0 = (f4 & 31) * 4;
    const float invN = 1.0f / (float)NN;
    float sc[4], sh[4];
    #pragma unroll
    for (int j = 0; j < 4; ++j) {
        int col = c0 + j;
        float mu  = bnsum[col] * invN;
        float var = bnsq[col] * invN - mu * mu;
        float k   = rsqrtf(var + BN_EPS) * gamma[col];
        sc[j] = k;
        sh[j] = beta[col] - mu * k;
    }
    float4 v = *(const float4*)&z[(size_t)f4 * 4];
    float4 o;
    o.x = fmaxf(fmaf(v.x, sc[0], sh[0]), 0.f);
    o.y = fmaxf(fmaf(v.y, sc[1], sh[1]), 0.f);
    o.z = fmaxf(fmaf(v.z, sc[2], sh[2]), 0.f);
    o.w = fmaxf(fmaf(v.w, sc[3], sh[3]), 0.f);
    *(float4*)&h[(size_t)f4 * 4] = o;
}

// ----------------------------------------------- final FC: h @ fc_w ----
__global__ __launch_bounds__(256) void k_fc(const float* __restrict__ h,
                                            const float* __restrict__ fc_w,
                                            const float* __restrict__ fc_b,
                                            float* __restrict__ out) {
    int wid  = (blockIdx.x * 256 + threadIdx.x) >> 6;
    int lane = threadIdx.x & 63;
    if (wid >= NN) return;
    float2 v = *(const float2*)&h[(size_t)wid * DIM + lane * 2];
    float2 wv = *(const float2*)&fc_w[lane * 2];
    float s = v.x * wv.x + v.y * wv.y;
    #pragma unroll
    for (int o = 32; o >= 1; o >>= 1) s += __shfl_down(s, o);
    if (lane == 0) out[wid] = s + fc_b[0];
}

// -------------------------------------------------------------- launch ----
extern "C" void kernel_launch(void* const* d_in, const int* in_sizes, int n_in,
                              void* d_out, int out_size, void* d_ws, size_t ws_size,
                              hipStream_t stream) {
    const float* x     = (const float*)d_in[0];
    const int*   src   = (const int*)d_in[1];          // edge_index[0]
    const int*   dst   = ((const int*)d_in[1]) + NE;   // edge_index[1]
    const float* W1    = (const float*)d_in[2];
    const float* b1    = (const float*)d_in[3];
    const float* W2    = (const float*)d_in[4];
    const float* b2    = (const float*)d_in[5];
    const float* gamma = (const float*)d_in[6];
    const float* beta  = (const float*)d_in[7];
    const float* fc_w  = (const float*)d_in[8];
    const float* fc_b  = (const float*)d_in[9];
    float* out = (float*)d_out;

    // workspace carve (16B aligned chunks)
    char* ws = (char*)d_ws;
    size_t o = 0;
    auto carve = [&](size_t bytes) {
        char* p = ws + o;
        o += (bytes + 15) & ~(size_t)15;
        return p;
    };
    int*   deg     = (int*)carve(NN * 4);
    int*   off     = (int*)carve((NN + 1) * 4);
    int*   cur     = (int*)carve(NN * 4);
    int*   csr     = (int*)carve(NE * 4);
    float* bnstats = (float*)carve(LAYERS * 2 * DIM * 4);  // [sum(3x128) | sq(3x128)]
    float* zbuf    = (float*)carve((size_t)NN * DIM * 4);
    float* h0      = (float*)carve((size_t)NN * DIM * 4);
    float* h1      = (float*)carve((size_t)NN * DIM * 4);

    // ---- CSR build (once per call) ----
    k_init<<<(NN + 255) / 256, 256, 0, stream>>>(deg, bnstats);
    k_hist<<<(NE + 255) / 256, 256, 0, stream>>>(dst, deg);
    k_scan<<<1, 1024, 0, stream>>>(deg, off);
    k_copy<<<(NN + 255) / 256, 256, 0, stream>>>(off, cur);
    k_fill<<<(NE + 255) / 256, 256, 0, stream>>>(src, dst, cur, csr);

    // ---- layers ----
    const float* hin = x;
    float* hbuf[2] = {h0, h1};
    const int nblk_mlp  = (NN + TM - 1) / TM;
    const int nblk_agg  = (NN * 64 + 255) / 256;           // wave per node
    const int nblk_norm = (NN * DIM / 4 + 255) / 256;

    for (int l = 0; l < LAYERS; ++l) {
        float* hout = hbuf[l & 1];
        k_agg<<<nblk_agg, 256, 0, stream>>>(hin, off, csr, zbuf);
        k_mlp<<<nblk_mlp, 256, 0, stream>>>(zbuf,
                                            W1 + (size_t)l * DIM * DIM, b1 + l * DIM,
                                            W2 + (size_t)l * DIM * DIM, b2 + l * DIM,
                                            bnstats + l * DIM,
                                            bnstats + LAYERS * DIM + l * DIM);
        k_norm<<<nblk_norm, 256, 0, stream>>>(zbuf,
                                              bnstats + l * DIM,
                                              bnstats + LAYERS * DIM + l * DIM,
                                              gamma + l * DIM, beta + l * DIM, hout);
        hin = hout;
    }

    // ---- final FC ----
    k_fc<<<(NN * 64 + 255) / 256, 256, 0, stream>>>(hin, fc_w, fc_b, out);
}

// Round 3
// 572.144 us; speedup vs baseline: 1.1449x; 1.1449x over previous
//
#include <hip/hip_runtime.h>
#include <math.h>

#define NN 50000
#define NE 600000
#define DIM 128
#define LAYERS 3
#define BN_EPS 1e-5f

#define SC_ELE 2048
#define NSCAN ((NN + SC_ELE - 1) / SC_ELE)   // 25 scan blocks

// ---------------------------------------------------------------- init ----
__global__ void k_init(int* __restrict__ deg, float* __restrict__ bnstats) {
    int i = blockIdx.x * 256 + threadIdx.x;
    if (i < NN) deg[i] = 0;
    if (i < LAYERS * 2 * DIM) bnstats[i] = 0.0f;
}

// ----------------------------------------------------------- histogram ----
__global__ void k_hist(const int* __restrict__ dst, int* __restrict__ deg) {
    int e = blockIdx.x * 256 + threadIdx.x;
    if (e < NE) atomicAdd(&deg[dst[e]], 1);
}

// ------------------------------------------- hierarchical scan, pass 1 ----
// 2048 elems/block; wave-level shfl scans; per-block exclusive prefix + sum
__global__ __launch_bounds__(1024) void k_scan1(const int* __restrict__ deg,
                                                int* __restrict__ part,
                                                int* __restrict__ bsum) {
    __shared__ int ws[16];
    const int t = threadIdx.x, lane = t & 63, wv = t >> 6;
    const int base = blockIdx.x * SC_ELE;
    const int e0 = base + 2 * t, e1 = e0 + 1;
    const int v0 = (e0 < NN) ? deg[e0] : 0;
    const int v1 = (e1 < NN) ? deg[e1] : 0;
    const int s = v0 + v1;
    int incl = s;
    #pragma unroll
    for (int o = 1; o < 64; o <<= 1) {
        int u = __shfl_up(incl, o);
        if (lane >= o) incl += u;
    }
    if (lane == 63) ws[wv] = incl;
    __syncthreads();
    if (wv == 0) {
        int x = (lane < 16) ? ws[lane] : 0;
        int ix = x;
        #pragma unroll
        for (int o = 1; o < 16; o <<= 1) {
            int u = __shfl_up(ix, o);
            if (lane >= o) ix += u;
        }
        if (lane < 16) ws[lane] = ix - x;          // exclusive wave offsets
        if (lane == 15) bsum[blockIdx.x] = ix;     // block total
    }
    __syncthreads();
    const int excl = incl - s + ws[wv];
    if (e0 < NN) part[e0] = excl;
    if (e1 < NN) part[e1] = excl + v0;
}

// ------------------------------------------- hierarchical scan, pass 2 ----
__global__ void k_scan2(const int* __restrict__ bsum, int* __restrict__ boff) {
    const int lane = threadIdx.x;                   // 64 threads, 1 block
    const int v = (lane < NSCAN) ? bsum[lane] : 0;
    int ix = v;
    #pragma unroll
    for (int o = 1; o < 64; o <<= 1) {
        int u = __shfl_up(ix, o);
        if (lane >= o) ix += u;
    }
    if (lane < NSCAN) boff[lane] = ix - v;
}

// --------------------------- hierarchical scan, pass 3 (+cur, +off[NN]) ----
__global__ void k_scan3(const int* __restrict__ part, const int* __restrict__ boff,
                        int* __restrict__ off, int* __restrict__ cur) {
    int i = blockIdx.x * 256 + threadIdx.x;
    if (i < NN) {
        int o = part[i] + boff[i >> 11];           // 2048 elems per scan block
        off[i] = o;
        cur[i] = o;
        if (i == 0) off[NN] = NE;                  // total is known a priori
    }
}

// ------------------------------------------------------------ csr fill ----
__global__ void k_fill(const int* __restrict__ src, const int* __restrict__ dst,
                       int* __restrict__ cur, int* __restrict__ csr) {
    int e = blockIdx.x * 256 + threadIdx.x;
    if (e < NE) {
        int p = atomicAdd(&cur[dst[e]], 1);
        csr[p] = src[e];
    }
}

// --------------------------------------- aggregate: z = h + sum_in h ----
// one wave per node; lane holds 2 features (float2) -> 512B coalesced rows
__global__ __launch_bounds__(256) void k_agg(const float* __restrict__ h,
                                             const int* __restrict__ off,
                                             const int* __restrict__ csr,
                                             float* __restrict__ z) {
    int wid  = (blockIdx.x * 256 + threadIdx.x) >> 6;
    int lane = threadIdx.x & 63;
    if (wid >= NN) return;
    const int start = off[wid], end = off[wid + 1];
    float2 acc = *(const float2*)&h[(size_t)wid * DIM + lane * 2];
    int i = start;
    for (; i + 1 < end; i += 2) {           // unroll-2: two loads in flight
        int s0 = csr[i], s1 = csr[i + 1];
        float2 v0 = *(const float2*)&h[(size_t)s0 * DIM + lane * 2];
        float2 v1 = *(const float2*)&h[(size_t)s1 * DIM + lane * 2];
        acc.x += v0.x + v1.x;
        acc.y += v0.y + v1.y;
    }
    if (i < end) {
        int s0 = csr[i];
        float2 v0 = *(const float2*)&h[(size_t)s0 * DIM + lane * 2];
        acc.x += v0.x;
        acc.y += v0.y;
    }
    *(float2*)&z[(size_t)wid * DIM + lane * 2] = acc;
}

// -------------------------------- fused MLP: relu(zW1+b1)W2+b2, stats ----
// 32-row tile; z updated in place (pre-BN); per-block BN partials -> atomics
#define TM 32
__global__ __launch_bounds__(256, 2) void k_mlp(float* __restrict__ z,
                                                const float* __restrict__ W1,
                                                const float* __restrict__ b1,
                                                const float* __restrict__ W2,
                                                const float* __restrict__ b2,
                                                float* __restrict__ bnsum,
                                                float* __restrict__ bnsq) {
    __shared__ float zt[TM][DIM];   // 16 KB  (A tile, then y1 tile, then stats scratch)
    __shared__ float w[DIM][DIM];   // 64 KB  (W1, then W2)
    const int t = threadIdx.x;
    const int c = t & 31;           // cols 4c..4c+3
    const int r = t >> 5;           // rows 4r..4r+3
    const int row0 = blockIdx.x * TM;

    // ---- load z tile (guarded) + W1 ----
    #pragma unroll
    for (int i = 0; i < 4; ++i) {
        int f4 = t + i * 256;
        int rr = f4 >> 5, c4 = f4 & 31;
        int g  = row0 + rr;
        float4 v = make_float4(0.f, 0.f, 0.f, 0.f);
        if (g < NN) v = *(const float4*)&z[(size_t)g * DIM + c4 * 4];
        *(float4*)&zt[rr][c4 * 4] = v;
    }
    #pragma unroll
    for (int i = 0; i < 16; ++i) {
        int f4 = t + i * 256;
        int k = f4 >> 5, j4 = f4 & 31;
        *(float4*)&w[k][j4 * 4] = *(const float4*)&W1[k * DIM + j4 * 4];
    }
    __syncthreads();

    // ---- GEMM1 ----
    float acc[4][4];
    #pragma unroll
    for (int i = 0; i < 4; ++i)
        #pragma unroll
        for (int j = 0; j < 4; ++j) acc[i][j] = 0.0f;

    for (int k = 0; k < DIM; k += 4) {
        float4 a4[4];
        #pragma unroll
        for (int i = 0; i < 4; ++i) a4[i] = *(const float4*)&zt[r * 4 + i][k];
        #pragma unroll
        for (int kk = 0; kk < 4; ++kk) {
            const float4 b = *(const float4*)&w[k + kk][c * 4];
            #pragma unroll
            for (int i = 0; i < 4; ++i) {
                const float a = (&a4[i].x)[kk];
                acc[i][0] = fmaf(a, b.x, acc[i][0]);
                acc[i][1] = fmaf(a, b.y, acc[i][1]);
                acc[i][2] = fmaf(a, b.z, acc[i][2]);
                acc[i][3] = fmaf(a, b.w, acc[i][3]);
            }
        }
    }
    __syncthreads();   // everyone done reading zt & w

    // ---- bias1 + relu -> y1 into zt; reload w with W2 ----
    const float4 bias1 = *(const float4*)&b1[c * 4];
    #pragma unroll
    for (int i = 0; i < 4; ++i) {
        float4 y;
        y.x = fmaxf(acc[i][0] + bias1.x, 0.f);
        y.y = fmaxf(acc[i][1] + bias1.y, 0.f);
        y.z = fmaxf(acc[i][2] + bias1.z, 0.f);
        y.w = fmaxf(acc[i][3] + bias1.w, 0.f);
        *(float4*)&zt[r * 4 + i][c * 4] = y;
    }
    #pragma unroll
    for (int i = 0; i < 16; ++i) {
        int f4 = t + i * 256;
        int k = f4 >> 5, j4 = f4 & 31;
        *(float4*)&w[k][j4 * 4] = *(const float4*)&W2[k * DIM + j4 * 4];
    }
    __syncthreads();

    // ---- GEMM2 ----
    #pragma unroll
    for (int i = 0; i < 4; ++i)
        #pragma unroll
        for (int j = 0; j < 4; ++j) acc[i][j] = 0.0f;

    for (int k = 0; k < DIM; k += 4) {
        float4 a4[4];
        #pragma unroll
        for (int i = 0; i < 4; ++i) a4[i] = *(const float4*)&zt[r * 4 + i][k];
        #pragma unroll
        for (int kk = 0; kk < 4; ++kk) {
            const float4 b = *(const float4*)&w[k + kk][c * 4];
            #pragma unroll
            for (int i = 0; i < 4; ++i) {
                const float a = (&a4[i].x)[kk];
                acc[i][0] = fmaf(a, b.x, acc[i][0]);
                acc[i][1] = fmaf(a, b.y, acc[i][1]);
                acc[i][2] = fmaf(a, b.z, acc[i][2]);
                acc[i][3] = fmaf(a, b.w, acc[i][3]);
            }
        }
    }
    __syncthreads();   // before reusing zt as stats scratch

    // ---- bias2, write z (pre-BN) back, per-thread stats ----
    const float4 bias2 = *(const float4*)&b2[c * 4];
    float s[4] = {0.f, 0.f, 0.f, 0.f};
    float q[4] = {0.f, 0.f, 0.f, 0.f};
    #pragma unroll
    for (int i = 0; i < 4; ++i) {
        int g = row0 + r * 4 + i;
        float4 zv;
        zv.x = acc[i][0] + bias2.x;
        zv.y = acc[i][1] + bias2.y;
        zv.z = acc[i][2] + bias2.z;
        zv.w = acc[i][3] + bias2.w;
        if (g < NN) {
            *(float4*)&z[(size_t)g * DIM + c * 4] = zv;
            s[0] += zv.x; s[1] += zv.y; s[2] += zv.z; s[3] += zv.w;
            q[0] += zv.x * zv.x; q[1] += zv.y * zv.y;
            q[2] += zv.z * zv.z; q[3] += zv.w * zv.w;
        }
    }
    // block reduce over the 8 row-groups via LDS, then one atomic per col
    float* scratch = &zt[0][0];     // 4096 floats: [0:1024)=sum, [1024:2048)=sq
    #pragma unroll
    for (int j = 0; j < 4; ++j) {
        scratch[r * DIM + c * 4 + j]        = s[j];
        scratch[1024 + r * DIM + c * 4 + j] = q[j];
    }
    __syncthreads();
    if (t < DIM) {
        float ss = 0.f, qq = 0.f;
        #pragma unroll
        for (int rr = 0; rr < 8; ++rr) {
            ss += scratch[rr * DIM + t];
            qq += scratch[1024 + rr * DIM + t];
        }
        atomicAdd(&bnsum[t], ss);
        atomicAdd(&bnsq[t], qq);
    }
}

// ------------------------------- BN finalize + normalize + relu -> h ----
__global__ __launch_bounds__(256) void k_norm(const float* __restrict__ z,
                                              const float* __restrict__ bnsum,
                                              const float* __restrict__ bnsq,
                                              const float* __restrict__ gamma,
                                              const float* __restrict__ beta,
                                              float* __restrict__ h) {
    int f4 = blockIdx.x * 256 + threadIdx.x;          // over N*DIM/4 float4
    if (f4 >= NN * DIM / 4) return;
    int c0 = (f4 & 31) * 4;
    const float invN = 1.0f / (float)NN;
    float sc[4], sh[4];
    #pragma unroll
    for (int j = 0; j < 4; ++j) {
        int col = c0 + j;
        float mu  = bnsum[col] * invN;
        float var = bnsq[col] * invN - mu * mu;
        float k   = rsqrtf(var + BN_EPS) * gamma[col];
        sc[j] = k;
        sh[j] = beta[col] - mu * k;
    }
    float4 v = *(const float4*)&z[(size_t)f4 * 4];
    float4 o;
    o.x = fmaxf(fmaf(v.x, sc[0], sh[0]), 0.f);
    o.y = fmaxf(fmaf(v.y, sc[1], sh[1]), 0.f);
    o.z = fmaxf(fmaf(v.z, sc[2], sh[2]), 0.f);
    o.w = fmaxf(fmaf(v.w, sc[3], sh[3]), 0.f);
    *(float4*)&h[(size_t)f4 * 4] = o;
}

// ----------------------------------------------- final FC: h @ fc_w ----
__global__ __launch_bounds__(256) void k_fc(const float* __restrict__ h,
                                            const float* __restrict__ fc_w,
                                            const float* __restrict__ fc_b,
                                            float* __restrict__ out) {
    int wid  = (blockIdx.x * 256 + threadIdx.x) >> 6;
    int lane = threadIdx.x & 63;
    if (wid >= NN) return;
    float2 v = *(const float2*)&h[(size_t)wid * DIM + lane * 2];
    float2 wv = *(const float2*)&fc_w[lane * 2];
    float s = v.x * wv.x + v.y * wv.y;
    #pragma unroll
    for (int o = 32; o >= 1; o >>= 1) s += __shfl_down(s, o);
    if (lane == 0) out[wid] = s + fc_b[0];
}

// -------------------------------------------------------------- launch ----
extern "C" void kernel_launch(void* const* d_in, const int* in_sizes, int n_in,
                              void* d_out, int out_size, void* d_ws, size_t ws_size,
                              hipStream_t stream) {
    const float* x     = (const float*)d_in[0];
    const int*   src   = (const int*)d_in[1];          // edge_index[0]
    const int*   dst   = ((const int*)d_in[1]) + NE;   // edge_index[1]
    const float* W1    = (const float*)d_in[2];
    const float* b1    = (const float*)d_in[3];
    const float* W2    = (const float*)d_in[4];
    const float* b2    = (const float*)d_in[5];
    const float* gamma = (const float*)d_in[6];
    const float* beta  = (const float*)d_in[7];
    const float* fc_w  = (const float*)d_in[8];
    const float* fc_b  = (const float*)d_in[9];
    float* out = (float*)d_out;

    // workspace carve (16B aligned chunks)
    char* ws = (char*)d_ws;
    size_t o = 0;
    auto carve = [&](size_t bytes) {
        char* p = ws + o;
        o += (bytes + 15) & ~(size_t)15;
        return p;
    };
    int*   deg     = (int*)carve(NN * 4);
    int*   off     = (int*)carve((NN + 1) * 4);
    int*   cur     = (int*)carve(NN * 4);
    int*   csr     = (int*)carve(NE * 4);
    int*   part    = (int*)carve(NN * 4);
    int*   bsum    = (int*)carve(NSCAN * 4);
    int*   boff    = (int*)carve(NSCAN * 4);
    float* bnstats = (float*)carve(LAYERS * 2 * DIM * 4);  // [sum(3x128) | sq(3x128)]
    float* zbuf    = (float*)carve((size_t)NN * DIM * 4);
    float* h0      = (float*)carve((size_t)NN * DIM * 4);
    float* h1      = (float*)carve((size_t)NN * DIM * 4);

    // ---- CSR build (once per call) ----
    k_init<<<(NN + 255) / 256, 256, 0, stream>>>(deg, bnstats);
    k_hist<<<(NE + 255) / 256, 256, 0, stream>>>(dst, deg);
    k_scan1<<<NSCAN, 1024, 0, stream>>>(deg, part, bsum);
    k_scan2<<<1, 64, 0, stream>>>(bsum, boff);
    k_scan3<<<(NN + 255) / 256, 256, 0, stream>>>(part, boff, off, cur);
    k_fill<<<(NE + 255) / 256, 256, 0, stream>>>(src, dst, cur, csr);

    // ---- layers ----
    const float* hin = x;
    float* hbuf[2] = {h0, h1};
    const int nblk_mlp  = (NN + TM - 1) / TM;
    const int nblk_agg  = (NN * 64 + 255) / 256;           // wave per node
    const int nblk_norm = (NN * DIM / 4 + 255) / 256;

    for (int l = 0; l < LAYERS; ++l) {
        float* hout = hbuf[l & 1];
        k_agg<<<nblk_agg, 256, 0, stream>>>(hin, off, csr, zbuf);
        k_mlp<<<nblk_mlp, 256, 0, stream>>>(zbuf,
                                            W1 + (size_t)l * DIM * DIM, b1 + l * DIM,
                                            W2 + (size_t)l * DIM * DIM, b2 + l * DIM,
                                            bnstats + l * DIM,
                                            bnstats + LAYERS * DIM + l * DIM);
        k_norm<<<nblk_norm, 256, 0, stream>>>(zbuf,
                                              bnstats + l * DIM,
                                              bnstats + LAYERS * DIM + l * DIM,
                                              gamma + l * DIM, beta + l * DIM, hout);
        hin = hout;
    }

    // ---- final FC ----
    k_fc<<<(NN * 64 + 255) / 256, 256, 0, stream>>>(hin, fc_w, fc_b, out);
}